// Round 1
// 496.319 us; speedup vs baseline: 1.1208x; 1.1208x over previous
//
#include <hip/hip_runtime.h>
#include <cstdint>

#define S_LEN 2048
#define D_DIM 4096
#define NHEAD 32
#define NKVH  8
#define HDIM  128
#define NQKV  6144

typedef __bf16 bf16x8 __attribute__((ext_vector_type(8)));
typedef __bf16 bf16x2 __attribute__((ext_vector_type(2)));
typedef float floatx4 __attribute__((ext_vector_type(4)));
typedef unsigned short u16;
typedef unsigned int u32;

__device__ __forceinline__ u16 f2bf(float f) {
  u32 u = __builtin_bit_cast(u32, f);
  u += 0x7fffu + ((u >> 16) & 1u);
  return (u16)(u >> 16);
}
__device__ __forceinline__ float bf2f(u16 h) {
  u32 u = ((u32)h) << 16;
  return __builtin_bit_cast(float, u);
}
__device__ __forceinline__ u32 pack2(float a, float b) {
  bf16x2 t;
  t[0] = (__bf16)a;
  t[1] = (__bf16)b;
  return __builtin_bit_cast(u32, t);
}

// async global->LDS, 16B per lane; LDS dest = wave-uniform base + lane*16
__device__ __forceinline__ void gll16(const void* g, const void* l) {
  __builtin_amdgcn_global_load_lds(
      (const __attribute__((address_space(1))) u32*)(unsigned long long)(uintptr_t)g,
      (__attribute__((address_space(3))) u32*)(u32)(uintptr_t)l, 16, 0, 0);
}

// ---------------- prep: x cast + all 4 weight transposes, one launch ----------------

__global__ __launch_bounds__(256) void prep_kernel(const float* __restrict__ x,
                                                   const float* __restrict__ Wq,
                                                   const float* __restrict__ Wk,
                                                   const float* __restrict__ Wv,
                                                   const float* __restrict__ Wo,
                                                   u16* __restrict__ x_bf,
                                                   u16* __restrict__ wqkvT,
                                                   u16* __restrict__ woT) {
  int id = blockIdx.x;
  if (id < 8192) {
    int i = (id * 256 + (int)threadIdx.x) * 4;
    float4 v = *(const float4*)(x + i);
    u32 lo = (u32)f2bf(v.x) | ((u32)f2bf(v.y) << 16);
    u32 hi = (u32)f2bf(v.z) | ((u32)f2bf(v.w) << 16);
    *(uint2*)(x_bf + i) = make_uint2(lo, hi);
    return;
  }
  id -= 8192;
  __shared__ float tile[64][65];
  const float* src;
  u16* dst;
  int N;
  if (id < 4096) {
    src = Wq; dst = wqkvT; N = 4096;
  } else if (id < 5120) {
    src = Wk; dst = wqkvT + (size_t)4096 * 4096; N = 1024; id -= 4096;
  } else if (id < 6144) {
    src = Wv; dst = wqkvT + (size_t)5120 * 4096; N = 1024; id -= 5120;
  } else {
    src = Wo; dst = woT; N = 4096; id -= 6144;
  }
  const int nb = id / 64, kb = id % 64;
  const int k0 = kb * 64, n0 = nb * 64;
  const int t = threadIdx.x;
  const int c4 = (t & 15) * 4, r0 = t >> 4;
#pragma unroll
  for (int p = 0; p < 4; ++p) {
    int r = r0 + p * 16;
    float4 v = *(const float4*)(src + (size_t)(k0 + r) * N + n0 + c4);
    tile[r][c4 + 0] = v.x;
    tile[r][c4 + 1] = v.y;
    tile[r][c4 + 2] = v.z;
    tile[r][c4 + 3] = v.w;
  }
  __syncthreads();
#pragma unroll
  for (int p = 0; p < 4; ++p) {
    int rr = r0 + p * 16;
    u32 a = (u32)f2bf(tile[c4 + 0][rr]) | ((u32)f2bf(tile[c4 + 1][rr]) << 16);
    u32 b = (u32)f2bf(tile[c4 + 2][rr]) | ((u32)f2bf(tile[c4 + 3][rr]) << 16);
    *(uint2*)(dst + (size_t)(n0 + rr) * 4096 + k0 + c4) = make_uint2(a, b);
  }
}

// ---------------- rope + v-transpose, one launch ----------------

__global__ __launch_bounds__(256) void rope_vt_kernel(u16* __restrict__ qkv,
                                                      u16* __restrict__ vt) {
  int id = blockIdx.x;
  __shared__ u16 tile[64][65];
  if (id < 20480) {
    const int y = id >> 11, s = id & 2047;
    const int sub = threadIdx.x >> 6;
    const int i = threadIdx.x & 63;  // pair index
    const int hh = y * 4 + sub;
    const int colbase = (hh < NHEAD) ? hh * HDIM : D_DIM + (hh - NHEAD) * HDIM;
    u32* p = (u32*)(qkv + (size_t)s * NQKV + colbase) + i;
    u32 pr = *p;
    float x0 = bf2f((u16)(pr & 0xffffu));
    float x1 = bf2f((u16)(pr >> 16));
    float invf = expf(-(float)(2 * i) * (13.122363377404328f / 128.0f));
    float ang = (float)s * invf;
    float cs = cosf(ang), sn = sinf(ang);
    float o0 = x0 * cs - x1 * sn;
    float o1 = x0 * sn + x1 * cs;
    *p = (u32)f2bf(o0) | ((u32)f2bf(o1) << 16);
    return;
  }
  const int vb = id - 20480;  // 0..511
  const int hk = vb >> 6;
  const int d0 = ((vb >> 5) & 1) * 64;
  const int s0 = (vb & 31) * 64;
  const int t = threadIdx.x, c = t & 63, r0 = t >> 6;
#pragma unroll
  for (int p = 0; p < 16; ++p) {
    int r = r0 + p * 4;
    tile[r][c] = qkv[(size_t)(s0 + r) * NQKV + 5120 + hk * HDIM + d0 + c];
  }
  __syncthreads();
#pragma unroll
  for (int p = 0; p < 16; ++p) {
    int rr = r0 + p * 4;
    vt[((size_t)hk * HDIM + d0 + rr) * S_LEN + s0 + c] = tile[c][rr];
  }
}

// ---------------- GEMM: C[M,N] = A[M,K] * Bt[N,K]^T, BK=64 ----------------

template <bool BF16_OUT>
__global__ __launch_bounds__(256) void gemm_bt(const u16* __restrict__ A,
                                               const u16* __restrict__ Bt,
                                               void* __restrict__ Cout,
                                               int M, int N, int K, int lda, int ldb) {
  __shared__ u16 As[2][128 * 32];
  __shared__ u16 Bs[2][128 * 32];
  const int tid = threadIdx.x;
  const int w = tid >> 6, lane = tid & 63;
  const int quad = lane >> 4, l15 = lane & 15;
  const int m0 = blockIdx.y * 128, n0 = blockIdx.x * 128;
  const int wm = (w & 1) * 64, wn = (w >> 1) * 64;
  floatx4 acc[4][4];
#pragma unroll
  for (int mi = 0; mi < 4; ++mi)
#pragma unroll
    for (int ni = 0; ni < 4; ++ni)
#pragma unroll
      for (int j = 0; j < 4; ++j) acc[mi][ni][j] = 0.0f;

  const int srow = w * 32 + (lane >> 2);
  const int kcol = (lane & 3) * 8;
  const u16* pA0 = A + (size_t)(m0 + srow) * lda + kcol;
  const u16* pA1 = pA0 + (size_t)16 * lda;
  const u16* pB0 = Bt + (size_t)(n0 + srow) * ldb + kcol;
  const u16* pB1 = pB0 + (size_t)16 * ldb;

  for (int k0 = 0; k0 < K; k0 += 64) {
#pragma unroll
    for (int c = 0; c < 2; ++c) {
      gll16(pA0 + k0 + c * 32, As[c] + (w * 32) * 32);
      gll16(pA1 + k0 + c * 32, As[c] + (w * 32 + 16) * 32);
      gll16(pB0 + k0 + c * 32, Bs[c] + (w * 32) * 32);
      gll16(pB1 + k0 + c * 32, Bs[c] + (w * 32 + 16) * 32);
    }
    __syncthreads();
#pragma unroll
    for (int c2 = 0; c2 < 2; ++c2) {
      bf16x8 a[4], b[4];
#pragma unroll
      for (int mi = 0; mi < 4; ++mi)
        a[mi] = *(const bf16x8*)(As[c2] + (wm + mi * 16 + l15) * 32 + quad * 8);
#pragma unroll
      for (int ni = 0; ni < 4; ++ni)
        b[ni] = *(const bf16x8*)(Bs[c2] + (wn + ni * 16 + l15) * 32 + quad * 8);
#pragma unroll
      for (int mi = 0; mi < 4; ++mi)
#pragma unroll
        for (int ni = 0; ni < 4; ++ni)
          acc[mi][ni] = __builtin_amdgcn_mfma_f32_16x16x32_bf16(a[mi], b[ni], acc[mi][ni], 0, 0, 0);
    }
    __syncthreads();
  }
#pragma unroll
  for (int mi = 0; mi < 4; ++mi)
#pragma unroll
    for (int ni = 0; ni < 4; ++ni) {
      int row = m0 + wm + mi * 16 + quad * 4;
      int col = n0 + wn + ni * 16 + l15;
#pragma unroll
      for (int j = 0; j < 4; ++j) {
        if (BF16_OUT)
          ((u16*)Cout)[(size_t)(row + j) * N + col] = f2bf(acc[mi][ni][j]);
        else
          ((float*)Cout)[(size_t)(row + j) * N + col] = acc[mi][ni][j];
      }
    }
}

// ---------------- flash attention: 8 warps, dbuf prefetch, swizzled LDS ----------------
// Grid dim3(16, 32), 512 threads. Warp w owns q-rows [qb + w*16, qb + w*16 + 16).
// K tile [64][128] and V^T tile [128][64] in LDS, XOR-swizzled (^((row&7)*8) elems),
// staged linearly via global_load_lds with inverse-swizzled global source (rule 21).

__global__ __launch_bounds__(512, 4) void attn_kernel(const u16* __restrict__ qkv,
                                                      const u16* __restrict__ vt,
                                                      u16* __restrict__ attn_o) {
  __shared__ u16 Ks[2][64 * 128];   // 32 KB
  __shared__ u16 Vs[2][128 * 64];   // 32 KB
  __shared__ u16 Ps[8][16 * 64];    // 16 KB
  const int tid = threadIdx.x, w = tid >> 6, lane = tid & 63;
  const int quad = lane >> 4, l15 = lane & 15;
  const int h = blockIdx.y, hk = h >> 2;
  const int bx = (h & 16) ? blockIdx.x : (gridDim.x - 1 - blockIdx.x);
  const int qb = bx * 128;
  const int mq0 = qb + w * 16;
  const int qrow = mq0 + l15;
  const float scale2 = 0.12751744591813488f;  // log2(e)/sqrt(128)
  const int xsw = (l15 & 7) * 8;              // read-side XOR swizzle (elems)

  // Q fragments (B-operand of swapped QK^T)
  bf16x8 qfrag[4];
  {
    const u16* qp = qkv + (size_t)qrow * NQKV + h * HDIM + quad * 8;
#pragma unroll
    for (int c = 0; c < 4; ++c) qfrag[c] = *(const bf16x8*)(qp + c * 32);
  }

  floatx4 o[8];
#pragma unroll
  for (int nf = 0; nf < 8; ++nf)
#pragma unroll
    for (int j = 0; j < 4; ++j) o[nf][j] = 0.0f;
  float m_ = -1e30f, l_ = 0.0f;

  // ---- staging addresses (per-warp 1/8 of each tile, 2 gll16 each for K and V) ----
  // K: dest elem = w*1024 + 512*j + lane*8  -> row = w*8+4j+(lane>>4), slot=(lane&15)*8
  //    source col = slot ^ ((row&7)*8)  (inverse swizzle)
  const int krow0 = w * 8 + (lane >> 4);
  const int krow1 = krow0 + 4;
  const int kcol0 = ((lane & 15) * 8) ^ ((krow0 & 7) * 8);
  const int kcol1 = ((lane & 15) * 8) ^ ((krow1 & 7) * 8);
  const u16* kg0 = qkv + (size_t)krow0 * NQKV + (D_DIM + hk * HDIM) + kcol0;
  const u16* kg1 = qkv + (size_t)krow1 * NQKV + (D_DIM + hk * HDIM) + kcol1;
  // V: dest elem = w*1024 + 512*j + lane*8 -> d = w*16+8j+(lane>>3), slot=(lane&7)*8
  const int vd0 = w * 16 + (lane >> 3);
  const int vd1 = vd0 + 8;
  const int vcol = ((lane & 7) * 8) ^ (((lane >> 3) & 7) * 8);
  const u16* vg0 = vt + ((size_t)hk * HDIM + vd0) * S_LEN + vcol;
  const u16* vg1 = vt + ((size_t)hk * HDIM + vd1) * S_LEN + vcol;
  const int sofs0 = w * 1024 + lane * 8;
  const int sofs1 = sofs0 + 512;

  const int nkt = 2 * bx + 2;

#define STAGE(b, kb2)                                    \
  do {                                                   \
    gll16(kg0 + (size_t)(kb2)*NQKV, &Ks[b][sofs0]);      \
    gll16(kg1 + (size_t)(kb2)*NQKV, &Ks[b][sofs1]);      \
    gll16(vg0 + (kb2), &Vs[b][sofs0]);                   \
    gll16(vg1 + (kb2), &Vs[b][sofs1]);                   \
  } while (0)

  STAGE(0, 0);
  __syncthreads();

  for (int kt = 0; kt < nkt; ++kt) {
    const int kb = kt * 64;
    const int cur = kt & 1;
    if (kt + 1 < nkt) STAGE(cur ^ 1, kb + 64);  // async prefetch, lands by next barrier

    if (kb <= mq0 + 15) {
      const u16* ksb = Ks[cur];
      const u16* vsb = Vs[cur];
      floatx4 sn[4];
#pragma unroll
      for (int ki = 0; ki < 4; ++ki)
#pragma unroll
        for (int j = 0; j < 4; ++j) sn[ki][j] = 0.0f;

      __builtin_amdgcn_s_setprio(1);
#pragma unroll
      for (int ki = 0; ki < 4; ++ki) {
        if (kb + ki * 16 <= mq0 + 15) {
#pragma unroll
          for (int c = 0; c < 4; ++c) {
            bf16x8 kf = *(const bf16x8*)(ksb + (ki * 16 + l15) * 128 + ((c * 32 + quad * 8) ^ xsw));
            sn[ki] = __builtin_amdgcn_mfma_f32_16x16x32_bf16(kf, qfrag[c], sn[ki], 0, 0, 0);
          }
        }
      }
      __builtin_amdgcn_s_setprio(0);

      // ---- masked row-max (raw score domain) ----
      float mv = -1e30f;
      if (kb + 63 <= mq0) {  // interior tile: no causal mask needed
#pragma unroll
        for (int ki = 0; ki < 4; ++ki)
#pragma unroll
          for (int j = 0; j < 4; ++j) mv = fmaxf(mv, sn[ki][j]);
      } else {
#pragma unroll
        for (int ki = 0; ki < 4; ++ki) {
          if (kb + ki * 16 <= mq0 + 15) {
#pragma unroll
            for (int j = 0; j < 4; ++j) {
              int key = kb + ki * 16 + quad * 4 + j;
              float s = (key <= qrow) ? sn[ki][j] : -1e30f;
              sn[ki][j] = s;
              mv = fmaxf(mv, s);
            }
          }
        }
      }
      mv = fmaxf(mv, __shfl_xor(mv, 16, 64));
      mv = fmaxf(mv, __shfl_xor(mv, 32, 64));

      // ---- defer-max (T13): skip rescale when max growth <= 8 in log2 domain ----
      const float THRR = 62.73636f;  // 8 / scale2
      const bool skip = __all(mv <= m_ + THRR);
      float a_ = 1.0f, mb;
      if (skip) {
        mb = -m_ * scale2;
      } else {
        float mn = fmaxf(m_, mv);
        a_ = exp2f((m_ - mn) * scale2);
        m_ = mn;
        mb = -mn * scale2;
      }

      float ps = 0.0f;
      u16* psrow = &Ps[w][l15 * 64];
#pragma unroll
      for (int ki = 0; ki < 4; ++ki) {
        uint2 pk;
        if (kb + ki * 16 <= mq0 + 15) {
          float p0 = exp2f(fmaf(sn[ki][0], scale2, mb));
          float p1 = exp2f(fmaf(sn[ki][1], scale2, mb));
          float p2 = exp2f(fmaf(sn[ki][2], scale2, mb));
          float p3 = exp2f(fmaf(sn[ki][3], scale2, mb));
          ps += (p0 + p1) + (p2 + p3);
          pk.x = pack2(p0, p1);
          pk.y = pack2(p2, p3);
        } else {
          pk = make_uint2(0u, 0u);
        }
        *(uint2*)(psrow + ((ki * 16 + quad * 4) ^ xsw)) = pk;
      }
      ps += __shfl_xor(ps, 16, 64);
      ps += __shfl_xor(ps, 32, 64);

      if (skip) {
        l_ += ps;
      } else {
        l_ = l_ * a_ + ps;
        float al[4];
#pragma unroll
        for (int j = 0; j < 4; ++j) al[j] = __shfl(a_, quad * 4 + j, 16);
#pragma unroll
        for (int nf = 0; nf < 8; ++nf)
#pragma unroll
          for (int j = 0; j < 4; ++j) o[nf][j] *= al[j];
      }

      bf16x8 pa0 = *(const bf16x8*)(psrow + ((quad * 8) ^ xsw));
      bf16x8 pa1 = *(const bf16x8*)(psrow + ((32 + quad * 8) ^ xsw));

      __builtin_amdgcn_s_setprio(1);
#pragma unroll
      for (int nf = 0; nf < 8; ++nf) {
        const u16* vrow = vsb + (nf * 16 + l15) * 64;
        bf16x8 vb0 = *(const bf16x8*)(vrow + ((quad * 8) ^ xsw));
        bf16x8 vb1 = *(const bf16x8*)(vrow + ((32 + quad * 8) ^ xsw));
        o[nf] = __builtin_amdgcn_mfma_f32_16x16x32_bf16(pa0, vb0, o[nf], 0, 0, 0);
        o[nf] = __builtin_amdgcn_mfma_f32_16x16x32_bf16(pa1, vb1, o[nf], 0, 0, 0);
      }
      __builtin_amdgcn_s_setprio(0);
    }
    __syncthreads();  // compiler drains vmcnt(0): prefetch landed, reads of cur done
  }
#undef STAGE

  float linv = 1.0f / l_;
  float rl[4];
#pragma unroll
  for (int j = 0; j < 4; ++j) rl[j] = __shfl(linv, quad * 4 + j, 16);
#pragma unroll
  for (int nf = 0; nf < 8; ++nf)
#pragma unroll
    for (int j = 0; j < 4; ++j) {
      int row = mq0 + quad * 4 + j;
      int col = h * HDIM + nf * 16 + l15;
      attn_o[(size_t)row * D_DIM + col] = f2bf(o[nf][j] * rl[j]);
    }
}

// ---------------- launcher ----------------

extern "C" void kernel_launch(void* const* d_in, const int* in_sizes, int n_in,
                              void* d_out, int out_size, void* d_ws, size_t ws_size,
                              hipStream_t stream) {
  const float* x  = (const float*)d_in[0];
  const float* Wq = (const float*)d_in[1];
  const float* Wk = (const float*)d_in[2];
  const float* Wv = (const float*)d_in[3];
  const float* Wo = (const float*)d_in[4];
  float* out = (float*)d_out;
  char* ws = (char*)d_ws;
  const size_t MB = 1024 * 1024;
  u16* x_bf   = (u16*)(ws);              // 16 MB   [2048][4096]
  u16* wqkvT  = (u16*)(ws + 16 * MB);    // 48 MB   [6144][4096]
  u16* woT    = (u16*)(ws + 64 * MB);    // 32 MB   [4096][4096]
  u16* qkv    = (u16*)(ws + 96 * MB);    // 24 MB   [2048][6144]
  u16* vt     = (u16*)(ws + 120 * MB);   //  4 MB   [8][128][2048]
  u16* attn_o = (u16*)(ws + 124 * MB);   // 16 MB   [2048][4096]

  prep_kernel<<<8192 + 10240, 256, 0, stream>>>(x, Wq, Wk, Wv, Wo, x_bf, wqkvT, woT);
  gemm_bt<true><<<dim3(48, 16), 256, 0, stream>>>(x_bf, wqkvT, qkv, S_LEN, NQKV, D_DIM, D_DIM, D_DIM);
  rope_vt_kernel<<<20480 + 512, 256, 0, stream>>>(qkv, vt);
  attn_kernel<<<dim3(S_LEN / 128, NHEAD), 512, 0, stream>>>(qkv, vt, attn_o);
  gemm_bt<false><<<dim3(32, 16), 256, 0, stream>>>(attn_o, woT, out, S_LEN, D_DIM, D_DIM, D_DIM, D_DIM);
}

// Round 2
// 479.907 us; speedup vs baseline: 1.1591x; 1.0342x over previous
//
#include <hip/hip_runtime.h>
#include <cstdint>

#define S_LEN 2048
#define D_DIM 4096
#define NHEAD 32
#define NKVH  8
#define HDIM  128
#define NQKV  6144

typedef __bf16 bf16x8 __attribute__((ext_vector_type(8)));
typedef __bf16 bf16x2 __attribute__((ext_vector_type(2)));
typedef float floatx4 __attribute__((ext_vector_type(4)));
typedef unsigned short u16;
typedef unsigned int u32;

__device__ __forceinline__ u16 f2bf(float f) {
  u32 u = __builtin_bit_cast(u32, f);
  u += 0x7fffu + ((u >> 16) & 1u);
  return (u16)(u >> 16);
}
__device__ __forceinline__ float bf2f(u16 h) {
  u32 u = ((u32)h) << 16;
  return __builtin_bit_cast(float, u);
}
__device__ __forceinline__ u32 pack2(float a, float b) {
  bf16x2 t;
  t[0] = (__bf16)a;
  t[1] = (__bf16)b;
  return __builtin_bit_cast(u32, t);
}

// async global->LDS, 16B per lane; LDS dest = wave-uniform base + lane*16
__device__ __forceinline__ void gll16(const void* g, const void* l) {
  __builtin_amdgcn_global_load_lds(
      (const __attribute__((address_space(1))) u32*)(unsigned long long)(uintptr_t)g,
      (__attribute__((address_space(3))) u32*)(u32)(uintptr_t)l, 16, 0, 0);
}

// ---------------- prep: x cast + all 4 weight transposes, one launch ----------------

__global__ __launch_bounds__(256) void prep_kernel(const float* __restrict__ x,
                                                   const float* __restrict__ Wq,
                                                   const float* __restrict__ Wk,
                                                   const float* __restrict__ Wv,
                                                   const float* __restrict__ Wo,
                                                   u16* __restrict__ x_bf,
                                                   u16* __restrict__ wqkvT,
                                                   u16* __restrict__ woT) {
  int id = blockIdx.x;
  if (id < 8192) {
    int i = (id * 256 + (int)threadIdx.x) * 4;
    float4 v = *(const float4*)(x + i);
    u32 lo = (u32)f2bf(v.x) | ((u32)f2bf(v.y) << 16);
    u32 hi = (u32)f2bf(v.z) | ((u32)f2bf(v.w) << 16);
    *(uint2*)(x_bf + i) = make_uint2(lo, hi);
    return;
  }
  id -= 8192;
  __shared__ float tile[64][65];
  const float* src;
  u16* dst;
  int N;
  if (id < 4096) {
    src = Wq; dst = wqkvT; N = 4096;
  } else if (id < 5120) {
    src = Wk; dst = wqkvT + (size_t)4096 * 4096; N = 1024; id -= 4096;
  } else if (id < 6144) {
    src = Wv; dst = wqkvT + (size_t)5120 * 4096; N = 1024; id -= 5120;
  } else {
    src = Wo; dst = woT; N = 4096; id -= 6144;
  }
  const int nb = id / 64, kb = id % 64;
  const int k0 = kb * 64, n0 = nb * 64;
  const int t = threadIdx.x;
  const int c4 = (t & 15) * 4, r0 = t >> 4;
#pragma unroll
  for (int p = 0; p < 4; ++p) {
    int r = r0 + p * 16;
    float4 v = *(const float4*)(src + (size_t)(k0 + r) * N + n0 + c4);
    tile[r][c4 + 0] = v.x;
    tile[r][c4 + 1] = v.y;
    tile[r][c4 + 2] = v.z;
    tile[r][c4 + 3] = v.w;
  }
  __syncthreads();
#pragma unroll
  for (int p = 0; p < 4; ++p) {
    int rr = r0 + p * 16;
    u32 a = (u32)f2bf(tile[c4 + 0][rr]) | ((u32)f2bf(tile[c4 + 1][rr]) << 16);
    u32 b = (u32)f2bf(tile[c4 + 2][rr]) | ((u32)f2bf(tile[c4 + 3][rr]) << 16);
    *(uint2*)(dst + (size_t)(n0 + rr) * 4096 + k0 + c4) = make_uint2(a, b);
  }
}

// ---------------- rope + v-transpose, one launch ----------------

__global__ __launch_bounds__(256) void rope_vt_kernel(u16* __restrict__ qkv,
                                                      u16* __restrict__ vt) {
  int id = blockIdx.x;
  __shared__ u16 tile[64][65];
  if (id < 20480) {
    const int y = id >> 11, s = id & 2047;
    const int sub = threadIdx.x >> 6;
    const int i = threadIdx.x & 63;  // pair index
    const int hh = y * 4 + sub;
    const int colbase = (hh < NHEAD) ? hh * HDIM : D_DIM + (hh - NHEAD) * HDIM;
    u32* p = (u32*)(qkv + (size_t)s * NQKV + colbase) + i;
    u32 pr = *p;
    float x0 = bf2f((u16)(pr & 0xffffu));
    float x1 = bf2f((u16)(pr >> 16));
    float invf = expf(-(float)(2 * i) * (13.122363377404328f / 128.0f));
    float ang = (float)s * invf;
    float cs = cosf(ang), sn = sinf(ang);
    float o0 = x0 * cs - x1 * sn;
    float o1 = x0 * sn + x1 * cs;
    *p = (u32)f2bf(o0) | ((u32)f2bf(o1) << 16);
    return;
  }
  const int vb = id - 20480;  // 0..511
  const int hk = vb >> 6;
  const int d0 = ((vb >> 5) & 1) * 64;
  const int s0 = (vb & 31) * 64;
  const int t = threadIdx.x, c = t & 63, r0 = t >> 6;
#pragma unroll
  for (int p = 0; p < 16; ++p) {
    int r = r0 + p * 4;
    tile[r][c] = qkv[(size_t)(s0 + r) * NQKV + 5120 + hk * HDIM + d0 + c];
  }
  __syncthreads();
#pragma unroll
  for (int p = 0; p < 16; ++p) {
    int rr = r0 + p * 4;
    vt[((size_t)hk * HDIM + d0 + rr) * S_LEN + s0 + c] = tile[c][rr];
  }
}

// ---------------- GEMM 128x128 (kept for the output projection) ----------------

template <bool BF16_OUT>
__global__ __launch_bounds__(256) void gemm_bt(const u16* __restrict__ A,
                                               const u16* __restrict__ Bt,
                                               void* __restrict__ Cout,
                                               int M, int N, int K, int lda, int ldb) {
  __shared__ u16 As[2][128 * 32];
  __shared__ u16 Bs[2][128 * 32];
  const int tid = threadIdx.x;
  const int w = tid >> 6, lane = tid & 63;
  const int quad = lane >> 4, l15 = lane & 15;
  const int m0 = blockIdx.y * 128, n0 = blockIdx.x * 128;
  const int wm = (w & 1) * 64, wn = (w >> 1) * 64;
  floatx4 acc[4][4];
#pragma unroll
  for (int mi = 0; mi < 4; ++mi)
#pragma unroll
    for (int ni = 0; ni < 4; ++ni)
#pragma unroll
      for (int j = 0; j < 4; ++j) acc[mi][ni][j] = 0.0f;

  const int srow = w * 32 + (lane >> 2);
  const int kcol = (lane & 3) * 8;
  const u16* pA0 = A + (size_t)(m0 + srow) * lda + kcol;
  const u16* pA1 = pA0 + (size_t)16 * lda;
  const u16* pB0 = Bt + (size_t)(n0 + srow) * ldb + kcol;
  const u16* pB1 = pB0 + (size_t)16 * ldb;

  for (int k0 = 0; k0 < K; k0 += 64) {
#pragma unroll
    for (int c = 0; c < 2; ++c) {
      gll16(pA0 + k0 + c * 32, As[c] + (w * 32) * 32);
      gll16(pA1 + k0 + c * 32, As[c] + (w * 32 + 16) * 32);
      gll16(pB0 + k0 + c * 32, Bs[c] + (w * 32) * 32);
      gll16(pB1 + k0 + c * 32, Bs[c] + (w * 32 + 16) * 32);
    }
    __syncthreads();
#pragma unroll
    for (int c2 = 0; c2 < 2; ++c2) {
      bf16x8 a[4], b[4];
#pragma unroll
      for (int mi = 0; mi < 4; ++mi)
        a[mi] = *(const bf16x8*)(As[c2] + (wm + mi * 16 + l15) * 32 + quad * 8);
#pragma unroll
      for (int ni = 0; ni < 4; ++ni)
        b[ni] = *(const bf16x8*)(Bs[c2] + (wn + ni * 16 + l15) * 32 + quad * 8);
#pragma unroll
      for (int mi = 0; mi < 4; ++mi)
#pragma unroll
        for (int ni = 0; ni < 4; ++ni)
          acc[mi][ni] = __builtin_amdgcn_mfma_f32_16x16x32_bf16(a[mi], b[ni], acc[mi][ni], 0, 0, 0);
    }
    __syncthreads();
  }
#pragma unroll
  for (int mi = 0; mi < 4; ++mi)
#pragma unroll
    for (int ni = 0; ni < 4; ++ni) {
      int row = m0 + wm + mi * 16 + quad * 4;
      int col = n0 + wn + ni * 16 + l15;
#pragma unroll
      for (int j = 0; j < 4; ++j) {
        if (BF16_OUT)
          ((u16*)Cout)[(size_t)(row + j) * N + col] = f2bf(acc[mi][ni][j]);
        else
          ((float*)Cout)[(size_t)(row + j) * N + col] = acc[mi][ni][j];
      }
    }
}

// ---------------- GEMM 256x256, 8-phase, counted vmcnt, swizzled LDS ----------------
// 8 waves (2M x 4N), per-wave output 128x64 (acc[8][4]), BK=64 (2 k-chunks of 32).
// Fixed buffers: Ab[0]/Bb[0] hold even K-tiles, Ab[1]/Bb[1] odd.
// Iteration computes tile t (phases 1-4) and t+1 (phases 5-8); stage slots:
//  p1:(t+1,A0) p2:(t+1,A1) p3:(t+2,B0) p4:(t+2,B1) p5:(t+2,A0) p6:(t+2,A1) p7:(t+3,B0) p8:(t+3,B1)
// Each stage targets a region whose reads finished >=1 barrier earlier (B read at
// phase 1 of its half; A fully read by phase 4). vmcnt(4) at p4/p8 gates the next
// half's data (2 half-tiles = 4 loads stay in flight; never drained to 0).

template <bool BF16_OUT>
__global__ __launch_bounds__(512, 2) void gemm256_bt(const u16* __restrict__ A,
                                                     const u16* __restrict__ Bt,
                                                     void* __restrict__ Cout,
                                                     int M, int N, int K, int lda, int ldb) {
  __shared__ u16 Ab[2][16384];  // [256][64] per buffer
  __shared__ u16 Bb[2][16384];
  const int tid = threadIdx.x;
  const int w = tid >> 6, lane = tid & 63;
  const int quad = lane >> 4, l15 = lane & 15;
  const int wr = w >> 2, wc = w & 3;
  const int m0 = blockIdx.y * 256, n0 = blockIdx.x * 256;
  const int xsw = (l15 & 7) * 8;

  floatx4 acc[8][4];
#pragma unroll
  for (int mf = 0; mf < 8; ++mf)
#pragma unroll
    for (int nf = 0; nf < 4; ++nf)
#pragma unroll
      for (int j = 0; j < 4; ++j) acc[mf][nf][j] = 0.0f;

  // staging: thread covers row (h*128 + j*64 + tid>>3), swizzled col within 64
  const int srow = tid >> 3;
  const int scol = ((tid & 7) * 8) ^ ((srow & 7) * 8);
  const u16* gA = A + (size_t)(m0 + srow) * lda + scol;
  const u16* gB = Bt + (size_t)(n0 + srow) * ldb + scol;

#define SA(buf, h, tt)                                                                       \
  do {                                                                                       \
    gll16(gA + (size_t)((h)*128) * lda + (size_t)(tt)*64, &Ab[buf][(h)*8192 + w * 512]);     \
    gll16(gA + (size_t)((h)*128 + 64) * lda + (size_t)(tt)*64,                               \
          &Ab[buf][(h)*8192 + 4096 + w * 512]);                                              \
  } while (0)
#define SB(buf, h, tt)                                                                       \
  do {                                                                                       \
    gll16(gB + (size_t)((h)*128) * ldb + (size_t)(tt)*64, &Bb[buf][(h)*8192 + w * 512]);     \
    gll16(gB + (size_t)((h)*128 + 64) * ldb + (size_t)(tt)*64,                               \
          &Bb[buf][(h)*8192 + 4096 + w * 512]);                                              \
  } while (0)

  // prologue: tile 0 (A+B) + tile 1 (B); keep tile-1 B (4 loads) in flight
  SA(0, 0, 0);
  SA(0, 1, 0);
  SB(0, 0, 0);
  SB(0, 1, 0);
  SB(1, 0, 1);
  SB(1, 1, 1);
  asm volatile("s_waitcnt vmcnt(4)" ::: "memory");
  __builtin_amdgcn_s_barrier();

  const int NT = K >> 6;
  bf16x8 bfr[4][2];

#define GPH(AC, BC, MPAIR, LOADB, STAGEOP, VM)                                               \
  {                                                                                          \
    if (LOADB) {                                                                             \
      _Pragma("unroll") for (int nf = 0; nf < 4; ++nf)                                       \
        _Pragma("unroll") for (int kc = 0; kc < 2; ++kc)                                     \
          bfr[nf][kc] = *(const bf16x8*)((BC) + (wc * 64 + nf * 16 + l15) * 64 +             \
                                         ((kc * 32 + quad * 8) ^ xsw));                      \
    }                                                                                        \
    bf16x8 af[2][2];                                                                         \
    _Pragma("unroll") for (int mi = 0; mi < 2; ++mi)                                         \
      _Pragma("unroll") for (int kc = 0; kc < 2; ++kc)                                       \
        af[mi][kc] = *(const bf16x8*)((AC) + (wr * 128 + ((MPAIR)*2 + mi) * 16 + l15) * 64 + \
                                      ((kc * 32 + quad * 8) ^ xsw));                         \
    STAGEOP;                                                                                 \
    __builtin_amdgcn_sched_barrier(0);                                                       \
    __builtin_amdgcn_s_barrier();                                                            \
    asm volatile("s_waitcnt lgkmcnt(0)" ::: "memory");                                       \
    __builtin_amdgcn_sched_barrier(0);                                                       \
    __builtin_amdgcn_s_setprio(1);                                                           \
    _Pragma("unroll") for (int mi = 0; mi < 2; ++mi)                                         \
      _Pragma("unroll") for (int nf = 0; nf < 4; ++nf)                                       \
        _Pragma("unroll") for (int kc = 0; kc < 2; ++kc)                                     \
          acc[(MPAIR)*2 + mi][nf] = __builtin_amdgcn_mfma_f32_16x16x32_bf16(                 \
              af[mi][kc], bfr[nf][kc], acc[(MPAIR)*2 + mi][nf], 0, 0, 0);                    \
    __builtin_amdgcn_s_setprio(0);                                                           \
    if (VM) asm volatile("s_waitcnt vmcnt(4)" ::: "memory");                                 \
    __builtin_amdgcn_s_barrier();                                                            \
  }

  for (int t = 0; t < NT; t += 2) {
    const bool stg = (t + 2 < NT);
    // half A: tile t from buffer 0
    GPH(Ab[0], Bb[0], 0, true,  { SA(1, 0, t + 1); }, false)
    GPH(Ab[0], Bb[0], 1, false, { SA(1, 1, t + 1); }, false)
    GPH(Ab[0], Bb[0], 2, false, { if (stg) SB(0, 0, t + 2); }, false)
    GPH(Ab[0], Bb[0], 3, false, { if (stg) SB(0, 1, t + 2); }, true)
    // half B: tile t+1 from buffer 1
    GPH(Ab[1], Bb[1], 0, true,  { if (stg) SA(0, 0, t + 2); }, false)
    GPH(Ab[1], Bb[1], 1, false, { if (stg) SA(0, 1, t + 2); }, false)
    GPH(Ab[1], Bb[1], 2, false, { if (stg) SB(1, 0, t + 3); }, false)
    GPH(Ab[1], Bb[1], 3, false, { if (stg) SB(1, 1, t + 3); }, true)
  }
#undef GPH
#undef SA
#undef SB

#pragma unroll
  for (int mf = 0; mf < 8; ++mf)
#pragma unroll
    for (int nf = 0; nf < 4; ++nf) {
      int row = m0 + wr * 128 + mf * 16 + quad * 4;
      int col = n0 + wc * 64 + nf * 16 + l15;
#pragma unroll
      for (int j = 0; j < 4; ++j) {
        if (BF16_OUT)
          ((u16*)Cout)[(size_t)(row + j) * N + col] = f2bf(acc[mf][nf][j]);
        else
          ((float*)Cout)[(size_t)(row + j) * N + col] = acc[mf][nf][j];
      }
    }
}

// ---------------- flash attention: 8 warps, dbuf prefetch, swizzled LDS ----------------

__global__ __launch_bounds__(512, 4) void attn_kernel(const u16* __restrict__ qkv,
                                                      const u16* __restrict__ vt,
                                                      u16* __restrict__ attn_o) {
  __shared__ u16 Ks[2][64 * 128];   // 32 KB
  __shared__ u16 Vs[2][128 * 64];   // 32 KB
  __shared__ u16 Ps[8][16 * 64];    // 16 KB
  const int tid = threadIdx.x, w = tid >> 6, lane = tid & 63;
  const int quad = lane >> 4, l15 = lane & 15;
  const int h = blockIdx.y, hk = h >> 2;
  const int bx = (h & 16) ? blockIdx.x : (gridDim.x - 1 - blockIdx.x);
  const int qb = bx * 128;
  const int mq0 = qb + w * 16;
  const int qrow = mq0 + l15;
  const float scale2 = 0.12751744591813488f;  // log2(e)/sqrt(128)
  const int xsw = (l15 & 7) * 8;              // read-side XOR swizzle (elems)

  // Q fragments (B-operand of swapped QK^T)
  bf16x8 qfrag[4];
  {
    const u16* qp = qkv + (size_t)qrow * NQKV + h * HDIM + quad * 8;
#pragma unroll
    for (int c = 0; c < 4; ++c) qfrag[c] = *(const bf16x8*)(qp + c * 32);
  }

  floatx4 o[8];
#pragma unroll
  for (int nf = 0; nf < 8; ++nf)
#pragma unroll
    for (int j = 0; j < 4; ++j) o[nf][j] = 0.0f;
  float m_ = -1e30f, l_ = 0.0f;

  const int krow0 = w * 8 + (lane >> 4);
  const int krow1 = krow0 + 4;
  const int kcol0 = ((lane & 15) * 8) ^ ((krow0 & 7) * 8);
  const int kcol1 = ((lane & 15) * 8) ^ ((krow1 & 7) * 8);
  const u16* kg0 = qkv + (size_t)krow0 * NQKV + (D_DIM + hk * HDIM) + kcol0;
  const u16* kg1 = qkv + (size_t)krow1 * NQKV + (D_DIM + hk * HDIM) + kcol1;
  const int vd0 = w * 16 + (lane >> 3);
  const int vd1 = vd0 + 8;
  const int vcol = ((lane & 7) * 8) ^ (((lane >> 3) & 7) * 8);
  const u16* vg0 = vt + ((size_t)hk * HDIM + vd0) * S_LEN + vcol;
  const u16* vg1 = vt + ((size_t)hk * HDIM + vd1) * S_LEN + vcol;
  const int sofs0 = w * 1024 + lane * 8;
  const int sofs1 = sofs0 + 512;

  const int nkt = 2 * bx + 2;

#define STAGE(b, kb2)                                    \
  do {                                                   \
    gll16(kg0 + (size_t)(kb2)*NQKV, &Ks[b][sofs0]);      \
    gll16(kg1 + (size_t)(kb2)*NQKV, &Ks[b][sofs1]);      \
    gll16(vg0 + (kb2), &Vs[b][sofs0]);                   \
    gll16(vg1 + (kb2), &Vs[b][sofs1]);                   \
  } while (0)

  STAGE(0, 0);
  __syncthreads();

  for (int kt = 0; kt < nkt; ++kt) {
    const int kb = kt * 64;
    const int cur = kt & 1;
    if (kt + 1 < nkt) STAGE(cur ^ 1, kb + 64);  // async prefetch, lands by next barrier

    if (kb <= mq0 + 15) {
      const u16* ksb = Ks[cur];
      const u16* vsb = Vs[cur];
      floatx4 sn[4];
#pragma unroll
      for (int ki = 0; ki < 4; ++ki)
#pragma unroll
        for (int j = 0; j < 4; ++j) sn[ki][j] = 0.0f;

      __builtin_amdgcn_s_setprio(1);
#pragma unroll
      for (int ki = 0; ki < 4; ++ki) {
        if (kb + ki * 16 <= mq0 + 15) {
#pragma unroll
          for (int c = 0; c < 4; ++c) {
            bf16x8 kf = *(const bf16x8*)(ksb + (ki * 16 + l15) * 128 + ((c * 32 + quad * 8) ^ xsw));
            sn[ki] = __builtin_amdgcn_mfma_f32_16x16x32_bf16(kf, qfrag[c], sn[ki], 0, 0, 0);
          }
        }
      }
      __builtin_amdgcn_s_setprio(0);

      // ---- masked row-max (raw score domain) ----
      float mv = -1e30f;
      if (kb + 63 <= mq0) {  // interior tile: no causal mask needed
#pragma unroll
        for (int ki = 0; ki < 4; ++ki)
#pragma unroll
          for (int j = 0; j < 4; ++j) mv = fmaxf(mv, sn[ki][j]);
      } else {
#pragma unroll
        for (int ki = 0; ki < 4; ++ki) {
          if (kb + ki * 16 <= mq0 + 15) {
#pragma unroll
            for (int j = 0; j < 4; ++j) {
              int key = kb + ki * 16 + quad * 4 + j;
              float s = (key <= qrow) ? sn[ki][j] : -1e30f;
              sn[ki][j] = s;
              mv = fmaxf(mv, s);
            }
          }
        }
      }
      mv = fmaxf(mv, __shfl_xor(mv, 16, 64));
      mv = fmaxf(mv, __shfl_xor(mv, 32, 64));

      // ---- defer-max (T13): skip rescale when max growth <= 8 in log2 domain ----
      const float THRR = 62.73636f;  // 8 / scale2
      const bool skip = __all(mv <= m_ + THRR);
      float a_ = 1.0f, mb;
      if (skip) {
        mb = -m_ * scale2;
      } else {
        float mn = fmaxf(m_, mv);
        a_ = exp2f((m_ - mn) * scale2);
        m_ = mn;
        mb = -mn * scale2;
      }

      float ps = 0.0f;
      u16* psrow = &Ps[w][l15 * 64];
#pragma unroll
      for (int ki = 0; ki < 4; ++ki) {
        uint2 pk;
        if (kb + ki * 16 <= mq0 + 15) {
          float p0 = exp2f(fmaf(sn[ki][0], scale2, mb));
          float p1 = exp2f(fmaf(sn[ki][1], scale2, mb));
          float p2 = exp2f(fmaf(sn[ki][2], scale2, mb));
          float p3 = exp2f(fmaf(sn[ki][3], scale2, mb));
          ps += (p0 + p1) + (p2 + p3);
          pk.x = pack2(p0, p1);
          pk.y = pack2(p2, p3);
        } else {
          pk = make_uint2(0u, 0u);
        }
        *(uint2*)(psrow + ((ki * 16 + quad * 4) ^ xsw)) = pk;
      }
      ps += __shfl_xor(ps, 16, 64);
      ps += __shfl_xor(ps, 32, 64);

      if (skip) {
        l_ += ps;
      } else {
        l_ = l_ * a_ + ps;
        float al[4];
#pragma unroll
        for (int j = 0; j < 4; ++j) al[j] = __shfl(a_, quad * 4 + j, 16);
#pragma unroll
        for (int nf = 0; nf < 8; ++nf)
#pragma unroll
          for (int j = 0; j < 4; ++j) o[nf][j] *= al[j];
      }

      bf16x8 pa0 = *(const bf16x8*)(psrow + ((quad * 8) ^ xsw));
      bf16x8 pa1 = *(const bf16x8*)(psrow + ((32 + quad * 8) ^ xsw));

      __builtin_amdgcn_s_setprio(1);
#pragma unroll
      for (int nf = 0; nf < 8; ++nf) {
        const u16* vrow = vsb + (nf * 16 + l15) * 64;
        bf16x8 vb0 = *(const bf16x8*)(vrow + ((quad * 8) ^ xsw));
        bf16x8 vb1 = *(const bf16x8*)(vrow + ((32 + quad * 8) ^ xsw));
        o[nf] = __builtin_amdgcn_mfma_f32_16x16x32_bf16(pa0, vb0, o[nf], 0, 0, 0);
        o[nf] = __builtin_amdgcn_mfma_f32_16x16x32_bf16(pa1, vb1, o[nf], 0, 0, 0);
      }
      __builtin_amdgcn_s_setprio(0);
    }
    __syncthreads();  // drains vmcnt(0): prefetch landed, reads of cur done
  }
#undef STAGE

  float linv = 1.0f / l_;
  float rl[4];
#pragma unroll
  for (int j = 0; j < 4; ++j) rl[j] = __shfl(linv, quad * 4 + j, 16);
#pragma unroll
  for (int nf = 0; nf < 8; ++nf)
#pragma unroll
    for (int j = 0; j < 4; ++j) {
      int row = mq0 + quad * 4 + j;
      int col = h * HDIM + nf * 16 + l15;
      attn_o[(size_t)row * D_DIM + col] = f2bf(o[nf][j] * rl[j]);
    }
}

// ---------------- launcher ----------------

extern "C" void kernel_launch(void* const* d_in, const int* in_sizes, int n_in,
                              void* d_out, int out_size, void* d_ws, size_t ws_size,
                              hipStream_t stream) {
  const float* x  = (const float*)d_in[0];
  const float* Wq = (const float*)d_in[1];
  const float* Wk = (const float*)d_in[2];
  const float* Wv = (const float*)d_in[3];
  const float* Wo = (const float*)d_in[4];
  float* out = (float*)d_out;
  char* ws = (char*)d_ws;
  const size_t MB = 1024 * 1024;
  u16* x_bf   = (u16*)(ws);              // 16 MB   [2048][4096]
  u16* wqkvT  = (u16*)(ws + 16 * MB);    // 48 MB   [6144][4096]
  u16* woT    = (u16*)(ws + 64 * MB);    // 32 MB   [4096][4096]
  u16* qkv    = (u16*)(ws + 96 * MB);    // 24 MB   [2048][6144]
  u16* vt     = (u16*)(ws + 120 * MB);   //  4 MB   [8][128][2048]
  u16* attn_o = (u16*)(ws + 124 * MB);   // 16 MB   [2048][4096]

  prep_kernel<<<8192 + 10240, 256, 0, stream>>>(x, Wq, Wk, Wv, Wo, x_bf, wqkvT, woT);
  gemm256_bt<true><<<dim3(24, 8), 512, 0, stream>>>(x_bf, wqkvT, qkv, S_LEN, NQKV, D_DIM, D_DIM, D_DIM);
  rope_vt_kernel<<<20480 + 512, 256, 0, stream>>>(qkv, vt);
  attn_kernel<<<dim3(S_LEN / 128, NHEAD), 512, 0, stream>>>(qkv, vt, attn_o);
  gemm_bt<false><<<dim3(32, 16), 256, 0, stream>>>(attn_o, woT, out, S_LEN, D_DIM, D_DIM, D_DIM, D_DIM);
}

// Round 3
// 453.694 us; speedup vs baseline: 1.2261x; 1.0578x over previous
//
#include <hip/hip_runtime.h>
#include <cstdint>

#define S_LEN 2048
#define D_DIM 4096
#define NHEAD 32
#define NKVH  8
#define HDIM  128
#define NQKV  6144

typedef __bf16 bf16x8 __attribute__((ext_vector_type(8)));
typedef __bf16 bf16x2 __attribute__((ext_vector_type(2)));
typedef float floatx4 __attribute__((ext_vector_type(4)));
typedef unsigned short u16;
typedef unsigned int u32;

__device__ __forceinline__ u16 f2bf(float f) {
  u32 u = __builtin_bit_cast(u32, f);
  u += 0x7fffu + ((u >> 16) & 1u);
  return (u16)(u >> 16);
}
__device__ __forceinline__ float bf2f(u16 h) {
  u32 u = ((u32)h) << 16;
  return __builtin_bit_cast(float, u);
}
__device__ __forceinline__ u32 pack2(float a, float b) {
  bf16x2 t;
  t[0] = (__bf16)a;
  t[1] = (__bf16)b;
  return __builtin_bit_cast(u32, t);
}

// async global->LDS, 16B per lane; LDS dest = wave-uniform base + lane*16
__device__ __forceinline__ void gll16(const void* g, const void* l) {
  __builtin_amdgcn_global_load_lds(
      (const __attribute__((address_space(1))) u32*)(unsigned long long)(uintptr_t)g,
      (__attribute__((address_space(3))) u32*)(u32)(uintptr_t)l, 16, 0, 0);
}

// ---------------- prep: x cast + all 4 weight transposes, one launch ----------------

__global__ __launch_bounds__(256) void prep_kernel(const float* __restrict__ x,
                                                   const float* __restrict__ Wq,
                                                   const float* __restrict__ Wk,
                                                   const float* __restrict__ Wv,
                                                   const float* __restrict__ Wo,
                                                   u16* __restrict__ x_bf,
                                                   u16* __restrict__ wqkvT,
                                                   u16* __restrict__ woT) {
  int id = blockIdx.x;
  if (id < 8192) {
    int i = (id * 256 + (int)threadIdx.x) * 4;
    float4 v = *(const float4*)(x + i);
    u32 lo = (u32)f2bf(v.x) | ((u32)f2bf(v.y) << 16);
    u32 hi = (u32)f2bf(v.z) | ((u32)f2bf(v.w) << 16);
    *(uint2*)(x_bf + i) = make_uint2(lo, hi);
    return;
  }
  id -= 8192;
  __shared__ float tile[64][65];
  const float* src;
  u16* dst;
  int N;
  if (id < 4096) {
    src = Wq; dst = wqkvT; N = 4096;
  } else if (id < 5120) {
    src = Wk; dst = wqkvT + (size_t)4096 * 4096; N = 1024; id -= 4096;
  } else if (id < 6144) {
    src = Wv; dst = wqkvT + (size_t)5120 * 4096; N = 1024; id -= 5120;
  } else {
    src = Wo; dst = woT; N = 4096; id -= 6144;
  }
  const int nb = id / 64, kb = id % 64;
  const int k0 = kb * 64, n0 = nb * 64;
  const int t = threadIdx.x;
  const int c4 = (t & 15) * 4, r0 = t >> 4;
#pragma unroll
  for (int p = 0; p < 4; ++p) {
    int r = r0 + p * 16;
    float4 v = *(const float4*)(src + (size_t)(k0 + r) * N + n0 + c4);
    tile[r][c4 + 0] = v.x;
    tile[r][c4 + 1] = v.y;
    tile[r][c4 + 2] = v.z;
    tile[r][c4 + 3] = v.w;
  }
  __syncthreads();
#pragma unroll
  for (int p = 0; p < 4; ++p) {
    int rr = r0 + p * 16;
    u32 a = (u32)f2bf(tile[c4 + 0][rr]) | ((u32)f2bf(tile[c4 + 1][rr]) << 16);
    u32 b = (u32)f2bf(tile[c4 + 2][rr]) | ((u32)f2bf(tile[c4 + 3][rr]) << 16);
    *(uint2*)(dst + (size_t)(n0 + rr) * 4096 + k0 + c4) = make_uint2(a, b);
  }
}

// ---------------- rope + v-transpose, one launch ----------------

__global__ __launch_bounds__(256) void rope_vt_kernel(u16* __restrict__ qkv,
                                                      u16* __restrict__ vt) {
  int id = blockIdx.x;
  __shared__ u16 tile[64][65];
  if (id < 20480) {
    const int y = id >> 11, s = id & 2047;
    const int sub = threadIdx.x >> 6;
    const int i = threadIdx.x & 63;  // pair index
    const int hh = y * 4 + sub;
    const int colbase = (hh < NHEAD) ? hh * HDIM : D_DIM + (hh - NHEAD) * HDIM;
    u32* p = (u32*)(qkv + (size_t)s * NQKV + colbase) + i;
    u32 pr = *p;
    float x0 = bf2f((u16)(pr & 0xffffu));
    float x1 = bf2f((u16)(pr >> 16));
    float invf = expf(-(float)(2 * i) * (13.122363377404328f / 128.0f));
    float ang = (float)s * invf;
    float cs = cosf(ang), sn = sinf(ang);
    float o0 = x0 * cs - x1 * sn;
    float o1 = x0 * sn + x1 * cs;
    *p = (u32)f2bf(o0) | ((u32)f2bf(o1) << 16);
    return;
  }
  const int vb = id - 20480;  // 0..511
  const int hk = vb >> 6;
  const int d0 = ((vb >> 5) & 1) * 64;
  const int s0 = (vb & 31) * 64;
  const int t = threadIdx.x, c = t & 63, r0 = t >> 6;
#pragma unroll
  for (int p = 0; p < 16; ++p) {
    int r = r0 + p * 4;
    tile[r][c] = qkv[(size_t)(s0 + r) * NQKV + 5120 + hk * HDIM + d0 + c];
  }
  __syncthreads();
#pragma unroll
  for (int p = 0; p < 16; ++p) {
    int rr = r0 + p * 4;
    vt[((size_t)hk * HDIM + d0 + rr) * S_LEN + s0 + c] = tile[c][rr];
  }
}

// ------ GEMM BM=256 x BN=(NF16*64), single-barrier 8-window pipeline ------
// 8 waves (2M x 4N): per-wave output 128 x (NF16*16). BK=64, 2 K-tiles/iter.
// Window p: bar; lgkmcnt(0); MFMA(mpair); ds_read frags for next window; stage slot.
// Swap windows (1,5) read B-frags + A-mp0 post-barrier (buffer just validated).
// Stage slots: w1/w2: A(t+1)->Ab[1]; w3[/w4]: B(t+2)->Bb[0]; w5/w6: A(t+2)->Ab[0];
// w7[/w8]: B(t+3)->Bb[1]. Every stage is >=2 barriers after its target's last
// read-issue (WAR-safe with single barrier). Counted gates at w4/w8: vmcnt(NF16)
// drains exactly the data the next half reads; next B stays in flight.

template <int NF16, bool BF16_OUT>
__global__ __launch_bounds__(512, 2) void gemm256p(const u16* __restrict__ A,
                                                   const u16* __restrict__ Bt,
                                                   void* __restrict__ Cout,
                                                   int M, int N, int K, int lda, int ldb) {
  constexpr int WN = NF16 * 16;  // per-wave cols
  constexpr int BN = 4 * WN;     // 256 or 128
  __shared__ u16 Ab[2][16384];
  __shared__ u16 Bb[2][BN * 64];
  const int tid = threadIdx.x;
  const int w = tid >> 6, lane = tid & 63;
  const int quad = lane >> 4, l15 = lane & 15;
  const int wr = w >> 2, wc = w & 3;
  const int m0 = blockIdx.y * 256, n0 = blockIdx.x * BN;
  const int xsw = (l15 & 7) * 8;

  floatx4 acc[8][NF16];
#pragma unroll
  for (int mf = 0; mf < 8; ++mf)
#pragma unroll
    for (int nf = 0; nf < NF16; ++nf)
#pragma unroll
      for (int j = 0; j < 4; ++j) acc[mf][nf][j] = 0.0f;

  const int srow = tid >> 3;
  const int scol = ((tid & 7) * 8) ^ ((srow & 7) * 8);
  const u16* gA = A + (size_t)(m0 + srow) * lda + scol;
  const u16* gB = Bt + (size_t)(n0 + srow) * ldb + scol;

#define SA(buf, h, tt)                                                                         \
  do {                                                                                         \
    gll16(gA + (size_t)((h)*128) * lda + (size_t)(tt)*64, &Ab[buf][(h)*8192 + w * 512]);       \
    gll16(gA + (size_t)((h)*128 + 64) * lda + (size_t)(tt)*64,                                 \
          &Ab[buf][(h)*8192 + 4096 + w * 512]);                                                \
  } while (0)
#define SB(buf, h, tt)                                                                         \
  do {                                                                                         \
    gll16(gB + (size_t)((h)*128) * ldb + (size_t)(tt)*64, &Bb[buf][(h)*8192 + w * 512]);       \
    gll16(gB + (size_t)((h)*128 + 64) * ldb + (size_t)(tt)*64,                                 \
          &Bb[buf][(h)*8192 + 4096 + w * 512]);                                                \
  } while (0)

#define RD_B(BC)                                                                               \
  _Pragma("unroll") for (int nf = 0; nf < NF16; ++nf)                                          \
    _Pragma("unroll") for (int kc = 0; kc < 2; ++kc)                                           \
      bfr[nf][kc] = *(const bf16x8*)((BC) + (wc * WN + nf * 16 + l15) * 64 +                   \
                                     ((kc * 32 + quad * 8) ^ xsw));
#define RD_A(DST, AC, MP)                                                                      \
  _Pragma("unroll") for (int mi = 0; mi < 2; ++mi)                                             \
    _Pragma("unroll") for (int kc = 0; kc < 2; ++kc)                                           \
      (DST)[mi][kc] = *(const bf16x8*)((AC) + (wr * 128 + ((MP)*2 + mi) * 16 + l15) * 64 +     \
                                       ((kc * 32 + quad * 8) ^ xsw));
#define MM(MP, SRC)                                                                            \
  __builtin_amdgcn_s_setprio(1);                                                               \
  _Pragma("unroll") for (int mi = 0; mi < 2; ++mi)                                             \
    _Pragma("unroll") for (int nf = 0; nf < NF16; ++nf)                                        \
      _Pragma("unroll") for (int kc = 0; kc < 2; ++kc)                                         \
        acc[(MP)*2 + mi][nf] = __builtin_amdgcn_mfma_f32_16x16x32_bf16(                        \
            (SRC)[mi][kc], bfr[nf][kc], acc[(MP)*2 + mi][nf], 0, 0, 0);                        \
  __builtin_amdgcn_s_setprio(0);
#define LGKM0                                                                                  \
  asm volatile("s_waitcnt lgkmcnt(0)" ::: "memory");                                           \
  __builtin_amdgcn_sched_barrier(0);
#define SBAR                                                                                   \
  __builtin_amdgcn_sched_barrier(0);                                                           \
  __builtin_amdgcn_s_barrier();
#define VMGATE                                                                                 \
  if (NF16 == 4) { asm volatile("s_waitcnt vmcnt(4)" ::: "memory"); }                          \
  else           { asm volatile("s_waitcnt vmcnt(2)" ::: "memory"); }

  // prologue: tile0 A+B, tile1 B; drain tile0, keep tile1-B in flight
  SA(0, 0, 0);
  SA(0, 1, 0);
  SB(0, 0, 0);
  if (NF16 == 4) SB(0, 1, 0);
  SB(1, 0, 1);
  if (NF16 == 4) SB(1, 1, 1);
  VMGATE;

  const int NT = K >> 6;
  bf16x8 bfr[NF16][2], afA[2][2], afB[2][2];

  for (int t = 0; t < NT; t += 2) {
    const bool s2 = (t + 2 < NT), s3 = (t + 3 < NT);
    // w1 (swap -> buffers[0], tile t)
    SBAR;
    RD_B(Bb[0]);
    RD_A(afA, Ab[0], 0);
    LGKM0;
    MM(0, afA);
    RD_A(afB, Ab[0], 1);
    SA(1, 0, t + 1);
    // w2
    SBAR;
    LGKM0;
    MM(1, afB);
    RD_A(afA, Ab[0], 2);
    SA(1, 1, t + 1);
    // w3
    SBAR;
    LGKM0;
    MM(2, afA);
    RD_A(afB, Ab[0], 3);
    if (s2) SB(0, 0, t + 2);
    // w4
    SBAR;
    LGKM0;
    MM(3, afB);
    if (NF16 == 4) {
      if (s2) SB(0, 1, t + 2);
    }
    VMGATE;
    // w5 (swap -> buffers[1], tile t+1)
    SBAR;
    RD_B(Bb[1]);
    RD_A(afA, Ab[1], 0);
    LGKM0;
    MM(0, afA);
    RD_A(afB, Ab[1], 1);
    if (s2) SA(0, 0, t + 2);
    // w6
    SBAR;
    LGKM0;
    MM(1, afB);
    RD_A(afA, Ab[1], 2);
    if (s2) SA(0, 1, t + 2);
    // w7
    SBAR;
    LGKM0;
    MM(2, afA);
    RD_A(afB, Ab[1], 3);
    if (s3) SB(1, 0, t + 3);
    // w8
    SBAR;
    LGKM0;
    MM(3, afB);
    if (NF16 == 4) {
      if (s3) SB(1, 1, t + 3);
    }
    VMGATE;
  }
#undef SA
#undef SB
#undef RD_B
#undef RD_A
#undef MM
#undef LGKM0
#undef SBAR
#undef VMGATE

#pragma unroll
  for (int mf = 0; mf < 8; ++mf)
#pragma unroll
    for (int nf = 0; nf < NF16; ++nf) {
      int row = m0 + wr * 128 + mf * 16 + quad * 4;
      int col = n0 + wc * WN + nf * 16 + l15;
#pragma unroll
      for (int j = 0; j < 4; ++j) {
        if (BF16_OUT)
          ((u16*)Cout)[(size_t)(row + j) * N + col] = f2bf(acc[mf][nf][j]);
        else
          ((float*)Cout)[(size_t)(row + j) * N + col] = acc[mf][nf][j];
      }
    }
}

// ---------------- flash attention: 8 warps, dbuf prefetch, swizzled LDS ----------------

__global__ __launch_bounds__(512, 4) void attn_kernel(const u16* __restrict__ qkv,
                                                      const u16* __restrict__ vt,
                                                      u16* __restrict__ attn_o) {
  __shared__ u16 Ks[2][64 * 128];   // 32 KB
  __shared__ u16 Vs[2][128 * 64];   // 32 KB
  __shared__ u16 Ps[8][16 * 64];    // 16 KB
  const int tid = threadIdx.x, w = tid >> 6, lane = tid & 63;
  const int quad = lane >> 4, l15 = lane & 15;
  const int h = blockIdx.y, hk = h >> 2;
  const int bx = (h & 16) ? blockIdx.x : (gridDim.x - 1 - blockIdx.x);
  const int qb = bx * 128;
  const int mq0 = qb + w * 16;
  const int qrow = mq0 + l15;
  const float scale2 = 0.12751744591813488f;  // log2(e)/sqrt(128)
  const int xsw = (l15 & 7) * 8;              // read-side XOR swizzle (elems)

  // Q fragments (B-operand of swapped QK^T)
  bf16x8 qfrag[4];
  {
    const u16* qp = qkv + (size_t)qrow * NQKV + h * HDIM + quad * 8;
#pragma unroll
    for (int c = 0; c < 4; ++c) qfrag[c] = *(const bf16x8*)(qp + c * 32);
  }

  floatx4 o[8];
#pragma unroll
  for (int nf = 0; nf < 8; ++nf)
#pragma unroll
    for (int j = 0; j < 4; ++j) o[nf][j] = 0.0f;
  float m_ = -1e30f, l_ = 0.0f;

  const int krow0 = w * 8 + (lane >> 4);
  const int krow1 = krow0 + 4;
  const int kcol0 = ((lane & 15) * 8) ^ ((krow0 & 7) * 8);
  const int kcol1 = ((lane & 15) * 8) ^ ((krow1 & 7) * 8);
  const u16* kg0 = qkv + (size_t)krow0 * NQKV + (D_DIM + hk * HDIM) + kcol0;
  const u16* kg1 = qkv + (size_t)krow1 * NQKV + (D_DIM + hk * HDIM) + kcol1;
  const int vd0 = w * 16 + (lane >> 3);
  const int vd1 = vd0 + 8;
  const int vcol = ((lane & 7) * 8) ^ (((lane >> 3) & 7) * 8);
  const u16* vg0 = vt + ((size_t)hk * HDIM + vd0) * S_LEN + vcol;
  const u16* vg1 = vt + ((size_t)hk * HDIM + vd1) * S_LEN + vcol;
  const int sofs0 = w * 1024 + lane * 8;
  const int sofs1 = sofs0 + 512;

  const int nkt = 2 * bx + 2;

#define STAGE(b, kb2)                                    \
  do {                                                   \
    gll16(kg0 + (size_t)(kb2)*NQKV, &Ks[b][sofs0]);      \
    gll16(kg1 + (size_t)(kb2)*NQKV, &Ks[b][sofs1]);      \
    gll16(vg0 + (kb2), &Vs[b][sofs0]);                   \
    gll16(vg1 + (kb2), &Vs[b][sofs1]);                   \
  } while (0)

  STAGE(0, 0);
  __syncthreads();

  for (int kt = 0; kt < nkt; ++kt) {
    const int kb = kt * 64;
    const int cur = kt & 1;
    if (kt + 1 < nkt) STAGE(cur ^ 1, kb + 64);  // async prefetch, lands by next barrier

    if (kb <= mq0 + 15) {
      const u16* ksb = Ks[cur];
      const u16* vsb = Vs[cur];
      floatx4 sn[4];
#pragma unroll
      for (int ki = 0; ki < 4; ++ki)
#pragma unroll
        for (int j = 0; j < 4; ++j) sn[ki][j] = 0.0f;

      __builtin_amdgcn_s_setprio(1);
#pragma unroll
      for (int ki = 0; ki < 4; ++ki) {
        if (kb + ki * 16 <= mq0 + 15) {
#pragma unroll
          for (int c = 0; c < 4; ++c) {
            bf16x8 kf = *(const bf16x8*)(ksb + (ki * 16 + l15) * 128 + ((c * 32 + quad * 8) ^ xsw));
            sn[ki] = __builtin_amdgcn_mfma_f32_16x16x32_bf16(kf, qfrag[c], sn[ki], 0, 0, 0);
          }
        }
      }
      __builtin_amdgcn_s_setprio(0);

      // ---- masked row-max (raw score domain) ----
      float mv = -1e30f;
      if (kb + 63 <= mq0) {  // interior tile: no causal mask needed
#pragma unroll
        for (int ki = 0; ki < 4; ++ki)
#pragma unroll
          for (int j = 0; j < 4; ++j) mv = fmaxf(mv, sn[ki][j]);
      } else {
#pragma unroll
        for (int ki = 0; ki < 4; ++ki) {
          if (kb + ki * 16 <= mq0 + 15) {
#pragma unroll
            for (int j = 0; j < 4; ++j) {
              int key = kb + ki * 16 + quad * 4 + j;
              float s = (key <= qrow) ? sn[ki][j] : -1e30f;
              sn[ki][j] = s;
              mv = fmaxf(mv, s);
            }
          }
        }
      }
      mv = fmaxf(mv, __shfl_xor(mv, 16, 64));
      mv = fmaxf(mv, __shfl_xor(mv, 32, 64));

      // ---- defer-max (T13): skip rescale when max growth <= 8 in log2 domain ----
      const float THRR = 62.73636f;  // 8 / scale2
      const bool skip = __all(mv <= m_ + THRR);
      float a_ = 1.0f, mb;
      if (skip) {
        mb = -m_ * scale2;
      } else {
        float mn = fmaxf(m_, mv);
        a_ = exp2f((m_ - mn) * scale2);
        m_ = mn;
        mb = -mn * scale2;
      }

      float ps = 0.0f;
      u16* psrow = &Ps[w][l15 * 64];
#pragma unroll
      for (int ki = 0; ki < 4; ++ki) {
        uint2 pk;
        if (kb + ki * 16 <= mq0 + 15) {
          float p0 = exp2f(fmaf(sn[ki][0], scale2, mb));
          float p1 = exp2f(fmaf(sn[ki][1], scale2, mb));
          float p2 = exp2f(fmaf(sn[ki][2], scale2, mb));
          float p3 = exp2f(fmaf(sn[ki][3], scale2, mb));
          ps += (p0 + p1) + (p2 + p3);
          pk.x = pack2(p0, p1);
          pk.y = pack2(p2, p3);
        } else {
          pk = make_uint2(0u, 0u);
        }
        *(uint2*)(psrow + ((ki * 16 + quad * 4) ^ xsw)) = pk;
      }
      ps += __shfl_xor(ps, 16, 64);
      ps += __shfl_xor(ps, 32, 64);

      if (skip) {
        l_ += ps;
      } else {
        l_ = l_ * a_ + ps;
        float al[4];
#pragma unroll
        for (int j = 0; j < 4; ++j) al[j] = __shfl(a_, quad * 4 + j, 16);
#pragma unroll
        for (int nf = 0; nf < 8; ++nf)
#pragma unroll
          for (int j = 0; j < 4; ++j) o[nf][j] *= al[j];
      }

      bf16x8 pa0 = *(const bf16x8*)(psrow + ((quad * 8) ^ xsw));
      bf16x8 pa1 = *(const bf16x8*)(psrow + ((32 + quad * 8) ^ xsw));

      __builtin_amdgcn_s_setprio(1);
#pragma unroll
      for (int nf = 0; nf < 8; ++nf) {
        const u16* vrow = vsb + (nf * 16 + l15) * 64;
        bf16x8 vb0 = *(const bf16x8*)(vrow + ((quad * 8) ^ xsw));
        bf16x8 vb1 = *(const bf16x8*)(vrow + ((32 + quad * 8) ^ xsw));
        o[nf] = __builtin_amdgcn_mfma_f32_16x16x32_bf16(pa0, vb0, o[nf], 0, 0, 0);
        o[nf] = __builtin_amdgcn_mfma_f32_16x16x32_bf16(pa1, vb1, o[nf], 0, 0, 0);
      }
      __builtin_amdgcn_s_setprio(0);
    }
    __syncthreads();  // drains vmcnt(0): prefetch landed, reads of cur done
  }
#undef STAGE

  float linv = 1.0f / l_;
  float rl[4];
#pragma unroll
  for (int j = 0; j < 4; ++j) rl[j] = __shfl(linv, quad * 4 + j, 16);
#pragma unroll
  for (int nf = 0; nf < 8; ++nf)
#pragma unroll
    for (int j = 0; j < 4; ++j) {
      int row = mq0 + quad * 4 + j;
      int col = h * HDIM + nf * 16 + l15;
      attn_o[(size_t)row * D_DIM + col] = f2bf(o[nf][j] * rl[j]);
    }
}

// ---------------- launcher ----------------

extern "C" void kernel_launch(void* const* d_in, const int* in_sizes, int n_in,
                              void* d_out, int out_size, void* d_ws, size_t ws_size,
                              hipStream_t stream) {
  const float* x  = (const float*)d_in[0];
  const float* Wq = (const float*)d_in[1];
  const float* Wk = (const float*)d_in[2];
  const float* Wv = (const float*)d_in[3];
  const float* Wo = (const float*)d_in[4];
  float* out = (float*)d_out;
  char* ws = (char*)d_ws;
  const size_t MB = 1024 * 1024;
  u16* x_bf   = (u16*)(ws);              // 16 MB   [2048][4096]
  u16* wqkvT  = (u16*)(ws + 16 * MB);    // 48 MB   [6144][4096]
  u16* woT    = (u16*)(ws + 64 * MB);    // 32 MB   [4096][4096]
  u16* qkv    = (u16*)(ws + 96 * MB);    // 24 MB   [2048][6144]
  u16* vt     = (u16*)(ws + 120 * MB);   //  4 MB   [8][128][2048]
  u16* attn_o = (u16*)(ws + 124 * MB);   // 16 MB   [2048][4096]

  prep_kernel<<<8192 + 10240, 256, 0, stream>>>(x, Wq, Wk, Wv, Wo, x_bf, wqkvT, woT);
  gemm256p<4, true><<<dim3(24, 8), 512, 0, stream>>>(x_bf, wqkvT, qkv, S_LEN, NQKV, D_DIM, D_DIM, D_DIM);
  rope_vt_kernel<<<20480 + 512, 256, 0, stream>>>(qkv, vt);
  attn_kernel<<<dim3(S_LEN / 128, NHEAD), 512, 0, stream>>>(qkv, vt, attn_o);
  gemm256p<2, false><<<dim3(32, 8), 512, 0, stream>>>(attn_o, woT, out, S_LEN, D_DIM, D_DIM, D_DIM, D_DIM);
}